// Round 10
// baseline (196.034 us; speedup 1.0000x reference)
//
#include <hip/hip_runtime.h>
#include <hip/hip_bf16.h>

// GCNConv: out = D * (A @ (D * (X@W))) + bias,  D = rsqrt(rowsum(A)+1)
// N=100000, E=640000, C=128.
// R2..R11: 1285 -> 203us. R12: coop mega-kernel FAILED (453us), reverted.
// R13: fixed-slot CSR (one u64 atomic -> slot+deg), 3 launches, 195us.
// R14: conflict-free Wt staging via init kernel (bank conflicts 4.2M->262K),
//      189.6us. build_gemm 54us but ALL pipes idle (Occ 16.5%: gemm is only
//      512 blocks = 2/CU = 8 waves/CU; LDS allows 4 blocks/CU).
// R15: TLP/MLP pass. gemm 1024 persistent blocks (4/CU, 16 waves/CU); build
//      4 edges/thread (4-deep atomic MLP); gather issues first-4 slot loads
//      concurrently with packed[n]. (R16 = identical resubmit: container
//      failed twice, never ran.)

#define N_CH 128
#define WT_LD 136  // padded LDS row stride (ushorts): banks (4m+4q)%32 -> 2-way max
#define FIXS 16777216.0f  // 2^24
#define KMAX 64   // fixed slots per node row

typedef __attribute__((ext_vector_type(8))) short short8;
typedef __attribute__((ext_vector_type(4))) float f32x4;
typedef __attribute__((ext_vector_type(4))) unsigned short ushort4v;

__device__ inline unsigned short f2bf(float f) {
    unsigned u = __float_as_uint(f);
    return (unsigned short)((u + 0x7FFFu + ((u >> 16) & 1u)) >> 16);  // RNE
}
__device__ inline float bf2f(unsigned short h) {
    return __uint_as_float(((unsigned)h) << 16);
}

// ---- init: packed[i]=0; Wt[n][k]=bf16(W[k][n]) (coalesced writes) --------
__global__ __launch_bounds__(256) void init_kernel(const float* __restrict__ W,
                                                   unsigned short* __restrict__ Wt,
                                                   unsigned long long* __restrict__ packed,
                                                   int N) {
    int gid = blockIdx.x * 256 + threadIdx.x;
    for (int i = gid; i < N; i += (int)gridDim.x * 256) packed[i] = 0ULL;
    if (gid < N_CH * N_CH) {
        int n = gid >> 7, k = gid & 127;   // consecutive threads -> consecutive k
        Wt[n * N_CH + k] = f2bf(W[k * N_CH + n]);  // coalesced write; read L1-cached
    }
}

// ---- fused dispatch: gemm blocks [0,gemmBlocks) + build blocks after -----
// gemm: Ybf[n,:] = bf16(X[n,:] @ W), swapped-operand MFMA (lane&15 = X row,
//   (lane>>4)*4+reg = out col in chunk tt). Persistent waves over 16-row
//   tiles, next tile's X prefetched into regs. Wt staged via short8 copy.
// build: per edge ONE u64 atomic: hi32 ++ -> slot, lo32 += val fix8.24 (deg).
//   epack[row*KMAX + slot] = {col, val}. 4 edges/thread (4-deep MLP).
__global__ __launch_bounds__(256) void build_gemm_kernel(
        const int* __restrict__ row, const int* __restrict__ col,
        const float* __restrict__ vals, const float* __restrict__ X,
        const unsigned short* __restrict__ Wt,
        unsigned long long* __restrict__ packed, uint2* __restrict__ epack,
        unsigned short* __restrict__ Ybf, int N, int E, int gemmBlocks) {
    __shared__ unsigned short Wl[N_CH * WT_LD];  // 34 KB

    const int t = threadIdx.x;

    if ((int)blockIdx.x >= gemmBlocks) {
        // ---- build part: 4 edges/thread, independent atomics in flight ----
        int e0 = (blockIdx.x - gemmBlocks) * 1024 + t;
#pragma unroll
        for (int j = 0; j < 4; ++j) {
            int e = e0 + j * 256;
            if (e < E) {
                int r = row[e];
                float v = vals[e];
                unsigned fx = (unsigned)(v * FIXS);
                unsigned long long old =
                    atomicAdd(&packed[r], (1ULL << 32) | (unsigned long long)fx);
                unsigned slot = (unsigned)(old >> 32);
                if (slot < KMAX)
                    epack[(size_t)r * KMAX + slot] =
                        make_uint2((unsigned)col[e], __float_as_uint(v));
            }
        }
        return;
    }

    // ---- gemm part ----
    // stage Wt (16384 ushorts = 2048 short8 chunks, 8 per thread; conflict-free)
    const short8* Wg = (const short8*)Wt;
#pragma unroll
    for (int j = 0; j < 8; ++j) {
        int idx = t + 256 * j;          // chunk id
        int r = idx >> 4, cc = idx & 15;
        *(short8*)(Wl + r * WT_LD + cc * 8) = Wg[idx];
    }
    __syncthreads();

    const int lane = t & 63;
    const int wv = t >> 6;
    const int m = lane & 15;   // X row within tile; W-fragment row select
    const int q = lane >> 4;   // k-subchunk; also output col group (q*4+reg)

    const int tiles = (N + 15) / 16;
    const int totalWaves = gemmBlocks * 4;
    int tile = blockIdx.x * 4 + wv;
    if (tile >= tiles) return;

    // prologue: first tile's X rows (raw f32)
    f32x4 pl[4], ph[4];
    {
        int rr = tile * 16 + m;
        if (rr >= N) rr = N - 1;
        const float* xr = X + (size_t)rr * N_CH + q * 8;
#pragma unroll
        for (int c = 0; c < 4; ++c) {
            pl[c] = *(const f32x4*)(xr + c * 32);
            ph[c] = *(const f32x4*)(xr + c * 32 + 4);
        }
    }

    while (true) {
        const int next = tile + totalWaves;
        const bool hasNext = next < tiles;

        // issue next tile's X loads early (hide under cvt+MFMA)
        f32x4 ql[4], qh[4];
        if (hasNext) {
            int rr2 = next * 16 + m;
            if (rr2 >= N) rr2 = N - 1;
            const float* xr2 = X + (size_t)rr2 * N_CH + q * 8;
#pragma unroll
            for (int c = 0; c < 4; ++c) {
                ql[c] = *(const f32x4*)(xr2 + c * 32);
                qh[c] = *(const f32x4*)(xr2 + c * 32 + 4);
            }
        }

        // cvt current tile f32 -> bf16 fragments
        short8 a[4];
#pragma unroll
        for (int c = 0; c < 4; ++c) {
            short8 v;
            v[0] = (short)f2bf(pl[c][0]); v[1] = (short)f2bf(pl[c][1]);
            v[2] = (short)f2bf(pl[c][2]); v[3] = (short)f2bf(pl[c][3]);
            v[4] = (short)f2bf(ph[c][0]); v[5] = (short)f2bf(ph[c][1]);
            v[6] = (short)f2bf(ph[c][2]); v[7] = (short)f2bf(ph[c][3]);
            a[c] = v;
        }

        f32x4 acc[8];
#pragma unroll
        for (int tt = 0; tt < 8; ++tt) acc[tt] = (f32x4){0.f, 0.f, 0.f, 0.f};

#pragma unroll
        for (int tt = 0; tt < 8; ++tt) {
            const unsigned short* wrow = Wl + (tt * 16 + m) * WT_LD + q * 8;
#pragma unroll
            for (int c = 0; c < 4; ++c) {
                short8 b = *(const short8*)(wrow + c * 32);
                // swapped operands: D[i=W-row][j=X-row]
                acc[tt] = __builtin_amdgcn_mfma_f32_16x16x32_bf16(b, a[c], acc[tt], 0, 0, 0);
            }
        }

        const int rr = tile * 16 + m;
        if (rr < N) {
            unsigned short* yrow = Ybf + (size_t)rr * N_CH;
#pragma unroll
            for (int tt = 0; tt < 8; ++tt) {
                unsigned lo = (unsigned)f2bf(acc[tt][0]) |
                              ((unsigned)f2bf(acc[tt][1]) << 16);
                unsigned hi = (unsigned)f2bf(acc[tt][2]) |
                              ((unsigned)f2bf(acc[tt][3]) << 16);
                *(uint2*)(yrow + tt * 16 + q * 4) = make_uint2(lo, hi);
            }
        }

        if (!hasNext) break;
#pragma unroll
        for (int c = 0; c < 4; ++c) { pl[c] = ql[c]; ph[c] = qh[c]; }
        tile = next;
    }
}

// ---- gather: out[n,:] = dinv[n] * sum_j val_j*dinv[col_j]*Y[col_j,:] + b -
// cnt and deg both come from packed[n]; dinv computed on the fly (rsqrt).
// First 4 slot loads issued CONCURRENTLY with packed[n] (no dependence).
__global__ __launch_bounds__(256) void gather_kernel(
        const unsigned long long* __restrict__ packed,
        const uint2* __restrict__ epack,
        const unsigned short* __restrict__ Ybf,
        const float* __restrict__ bias,
        float* __restrict__ out, int N) {
    unsigned gid = blockIdx.x * 256u + threadIdx.x;
    int n = gid >> 5;
    if (n >= N) return;
    int lane = gid & 31;
    int c = lane * 4;

    const uint2* base = epack + (size_t)n * KMAX;
    // issue independently: packed[n] and the first 4 slots (always-valid mem)
    uint2 f0 = base[0];
    uint2 f1 = base[1];
    uint2 f2 = base[2];
    uint2 f3 = base[3];
    unsigned long long pk = packed[n];
    int cnt = (int)(pk >> 32);
    if (cnt > KMAX) cnt = KMAX;
    float dn = rsqrtf((float)(unsigned)(pk & 0xFFFFFFFFull) * (1.0f / FIXS) + 1.0f);

    float4 acc = make_float4(0.f, 0.f, 0.f, 0.f);
    int e = 0;
    if (cnt >= 4) {
        // consume the 4 prefetched slots
        unsigned long long k0 = packed[f0.x];
        unsigned long long k1 = packed[f1.x];
        unsigned long long k2 = packed[f2.x];
        unsigned long long k3 = packed[f3.x];
        ushort4v y0 = *(const ushort4v*)(Ybf + (size_t)f0.x * N_CH + c);
        ushort4v y1 = *(const ushort4v*)(Ybf + (size_t)f1.x * N_CH + c);
        ushort4v y2 = *(const ushort4v*)(Ybf + (size_t)f2.x * N_CH + c);
        ushort4v y3 = *(const ushort4v*)(Ybf + (size_t)f3.x * N_CH + c);
        float w0 = __uint_as_float(f0.y) *
                   rsqrtf((float)(unsigned)(k0 & 0xFFFFFFFFull) * (1.0f / FIXS) + 1.0f);
        float w1 = __uint_as_float(f1.y) *
                   rsqrtf((float)(unsigned)(k1 & 0xFFFFFFFFull) * (1.0f / FIXS) + 1.0f);
        float w2 = __uint_as_float(f2.y) *
                   rsqrtf((float)(unsigned)(k2 & 0xFFFFFFFFull) * (1.0f / FIXS) + 1.0f);
        float w3 = __uint_as_float(f3.y) *
                   rsqrtf((float)(unsigned)(k3 & 0xFFFFFFFFull) * (1.0f / FIXS) + 1.0f);
        acc.x += w0 * bf2f(y0[0]) + w1 * bf2f(y1[0]) + w2 * bf2f(y2[0]) + w3 * bf2f(y3[0]);
        acc.y += w0 * bf2f(y0[1]) + w1 * bf2f(y1[1]) + w2 * bf2f(y2[1]) + w3 * bf2f(y3[1]);
        acc.z += w0 * bf2f(y0[2]) + w1 * bf2f(y1[2]) + w2 * bf2f(y2[2]) + w3 * bf2f(y3[2]);
        acc.w += w0 * bf2f(y0[3]) + w1 * bf2f(y1[3]) + w2 * bf2f(y2[3]) + w3 * bf2f(y3[3]);
        e = 4;
        for (; e + 4 <= cnt; e += 4) {
            uint2 p0 = base[e + 0];
            uint2 p1 = base[e + 1];
            uint2 p2 = base[e + 2];
            uint2 p3 = base[e + 3];
            unsigned long long j0 = packed[p0.x];
            unsigned long long j1 = packed[p1.x];
            unsigned long long j2 = packed[p2.x];
            unsigned long long j3 = packed[p3.x];
            ushort4v z0 = *(const ushort4v*)(Ybf + (size_t)p0.x * N_CH + c);
            ushort4v z1 = *(const ushort4v*)(Ybf + (size_t)p1.x * N_CH + c);
            ushort4v z2 = *(const ushort4v*)(Ybf + (size_t)p2.x * N_CH + c);
            ushort4v z3 = *(const ushort4v*)(Ybf + (size_t)p3.x * N_CH + c);
            float v0 = __uint_as_float(p0.y) *
                       rsqrtf((float)(unsigned)(j0 & 0xFFFFFFFFull) * (1.0f / FIXS) + 1.0f);
            float v1 = __uint_as_float(p1.y) *
                       rsqrtf((float)(unsigned)(j1 & 0xFFFFFFFFull) * (1.0f / FIXS) + 1.0f);
            float v2 = __uint_as_float(p2.y) *
                       rsqrtf((float)(unsigned)(j2 & 0xFFFFFFFFull) * (1.0f / FIXS) + 1.0f);
            float v3 = __uint_as_float(p3.y) *
                       rsqrtf((float)(unsigned)(j3 & 0xFFFFFFFFull) * (1.0f / FIXS) + 1.0f);
            acc.x += v0 * bf2f(z0[0]) + v1 * bf2f(z1[0]) + v2 * bf2f(z2[0]) + v3 * bf2f(z3[0]);
            acc.y += v0 * bf2f(z0[1]) + v1 * bf2f(z1[1]) + v2 * bf2f(z2[1]) + v3 * bf2f(z3[1]);
            acc.z += v0 * bf2f(z0[2]) + v1 * bf2f(z1[2]) + v2 * bf2f(z2[2]) + v3 * bf2f(z3[2]);
            acc.w += v0 * bf2f(z0[3]) + v1 * bf2f(z1[3]) + v2 * bf2f(z2[3]) + v3 * bf2f(z3[3]);
        }
    }
    for (; e < cnt; ++e) {
        uint2 p = base[e];
        unsigned long long kk = packed[p.x];
        float w = __uint_as_float(p.y) *
                  rsqrtf((float)(unsigned)(kk & 0xFFFFFFFFull) * (1.0f / FIXS) + 1.0f);
        ushort4v y = *(const ushort4v*)(Ybf + (size_t)p.x * N_CH + c);
        acc.x += w * bf2f(y[0]);
        acc.y += w * bf2f(y[1]);
        acc.z += w * bf2f(y[2]);
        acc.w += w * bf2f(y[3]);
    }

    float4 b = ((const float4*)bias)[lane];
    float4 o;
    o.x = acc.x * dn + b.x;
    o.y = acc.y * dn + b.y;
    o.z = acc.z * dn + b.z;
    o.w = acc.w * dn + b.w;
    ((float4*)(out + (size_t)n * N_CH))[lane] = o;
}

extern "C" void kernel_launch(void* const* d_in, const int* in_sizes, int n_in,
                              void* d_out, int out_size, void* d_ws, size_t ws_size,
                              hipStream_t stream) {
    const int*   row  = (const int*)d_in[0];
    const int*   col  = (const int*)d_in[1];
    const float* vals = (const float*)d_in[2];
    const float* X    = (const float*)d_in[3];
    const float* W    = (const float*)d_in[4];
    const float* bias = (const float*)d_in[5];
    float* out = (float*)d_out;

    const int E = in_sizes[0];
    const int N = in_sizes[3] / N_CH;

    // workspace: epack N*KMAX uint2 (51.2MB) | Ybf N*128 bf16 (25.6MB)
    //            | packed N u64 (0.8MB) | Wt 128*128 bf16 (32KB)
    uint2*              epack  = (uint2*)d_ws;
    unsigned short*     Ybf    = (unsigned short*)(epack + (size_t)N * KMAX);
    unsigned long long* packed = (unsigned long long*)(Ybf + (size_t)N * N_CH);
    unsigned short*     Wt     = (unsigned short*)(packed + N);

    init_kernel<<<512, 256, 0, stream>>>(W, Wt, packed, N);

    const int gemmBlocks = 1024;                      // persistent, 4/CU (LDS cap)
    const int buildBlocks = (E + 1023) / 1024;        // 625, 4 edges/thread
    build_gemm_kernel<<<gemmBlocks + buildBlocks, 256, 0, stream>>>(
        row, col, vals, X, Wt, packed, epack, Ybf, N, E, gemmBlocks);

    unsigned gth = (unsigned)N * 32u;
    gather_kernel<<<(gth + 255) / 256, 256, 0, stream>>>(packed, epack, Ybf,
                                                         bias, out, N);
}